// Round 9
// baseline (270.077 us; speedup 1.0000x reference)
//
#include <hip/hip_runtime.h>

// LengthRegulator: expand x[B,L,D] along L per integer durations into out[B,T,D].
// B=64, L=256, D=512, T=max_length=1792. Out: (out [B,T,D] f32, max_length).
//
// v8 = v5 copy structure (best measured: 263.7us) + TILE 64->128.
// Measured decomposition (R5 REP diagnostic + floor 196us): kernel ~68us =
// copy ~50us (5.4 TB/s, near the 6.4 proven ceiling) + front-matter ~17us
// (ramp + per-block scan/scatter, paid by 1792 blocks). v7 showed scan
// micro-opts and read-dedupe are off the critical path / counterproductive
// (serial prev-chain). Single variable this round: halve the block count
// (TILE=128, 896 blocks) to halve front-matter. Copy loop byte-identical
// pattern to v5: interleaved frames, independent batch-4 loads, plain stores,
// XCD-locality swizzle (XCD k owns b in [8k,8k+8) -> 4MB x-panel per L2).

#define BB 64
#define LL 256
#define DD 512
#define TT 1792
#define D4 (DD / 4)          // 128 float4 per row
#define TILE 128             // frames per block; TT = 14 * TILE exact
#define NBT (TT / TILE)      // 14 t-blocks per b
#define NBLK (BB * NBT)      // 896 blocks

typedef float f32x4 __attribute__((ext_vector_type(4)));

__global__ __launch_bounds__(256) void length_regulator_kernel(
    const f32x4* __restrict__ x4,       // [B, L, D4]
    const int*   __restrict__ dur,      // [B, L]
    const int*   __restrict__ maxlen,   // [1]
    float*       __restrict__ out)      // [B*T*D + 1]
{
    __shared__ int wsum[4];
    __shared__ int idx_s[TILE];
    const int tid = threadIdx.x;

    // XCD-locality swizzle: XCD k owns b in [8k, 8k+8).
    const int bid  = blockIdx.x;
    const int virt = (bid & 7) * (NBLK / 8) + (bid >> 3);
    const int b    = virt / NBT;
    const int t0   = (virt % NBT) * TILE;

    // --- inclusive scan of durations: wave shuffle scan + 4-wave combine ---
    // ALPHA = 1.0 -> round(d * 1.0) == d
    int d = dur[b * LL + tid];
    int c = d;
    #pragma unroll
    for (int off = 1; off < 64; off <<= 1) {
        int u = __shfl_up(c, off, 64);
        if ((tid & 63) >= off) c += u;
    }
    if (tid < TILE) idx_s[tid] = -1;          // -1 = "zero frame"
    if ((tid & 63) == 63) wsum[tid >> 6] = c; // wave totals
    __syncthreads();
    {
        const int s0 = wsum[0], s1 = wsum[1], s2 = wsum[2], s3 = wsum[3];
        const int wid   = tid >> 6;
        const int total = s0 + s1 + s2 + s3;
        c += (wid > 0 ? s0 : 0) + (wid > 1 ? s1 : 0) + (wid > 2 ? s2 : 0);
        // all-zero row: d[0] = 1 -> cum[j] = 1 for all j
        if (total == 0) { c = 1; d = (tid == 0) ? 1 : 0; }
    }

    // --- scatter: thread j stamps idx over [c-d, c) ∩ [t0, t0+TILE) ---
    // Reproduces searchsorted(cum, t, 'right'). <= 7 LDS writes/thread.
    {
        const int lo = max(c - d, t0);
        const int hi = min(c, t0 + TILE);
        for (int t = lo; t < hi; ++t) idx_s[t - t0] = tid;
    }
    __syncthreads();

    // --- copy: 2 groups x 128 lanes; one D-row per group per iter ---
    // v5 pattern: interleaved frames, 4 independent loads in flight before
    // 4 stores (compile-time indices after unroll -> registers).
    const int group = tid >> 7;   // 0..1
    const int lane  = tid & 127;  // float4 index within row
    const f32x4 z   = (f32x4)(0.f);
    const f32x4* __restrict__ xrow = x4 + (size_t)b * LL * D4;
    f32x4* __restrict__ outb = (f32x4*)out + ((size_t)b * TT + t0) * D4;

    #pragma unroll
    for (int itb = 0; itb < TILE / 2; itb += 4) {
        const int ta = (itb + 0) * 2 + group;
        const int tb = (itb + 1) * 2 + group;
        const int tc = (itb + 2) * 2 + group;
        const int td = (itb + 3) * 2 + group;
        const int ia = idx_s[ta];
        const int ib = idx_s[tb];
        const int ic = idx_s[tc];
        const int ie = idx_s[td];
        f32x4 va = xrow[max(ia, 0) * D4 + lane];
        f32x4 vb = xrow[max(ib, 0) * D4 + lane];
        f32x4 vc = xrow[max(ic, 0) * D4 + lane];
        f32x4 ve = xrow[max(ie, 0) * D4 + lane];
        va = (ia >= 0) ? va : z;
        vb = (ib >= 0) ? vb : z;
        vc = (ic >= 0) ? vc : z;
        ve = (ie >= 0) ? ve : z;
        outb[ta * D4 + lane] = va;
        outb[tb * D4 + lane] = vb;
        outb[tc * D4 + lane] = vc;
        outb[td * D4 + lane] = ve;
    }

    // --- output 1: max_length as float, one thread writes it ---
    if (virt == 0 && tid == 0) {
        out[(size_t)BB * TT * DD] = (float)maxlen[0];
    }
}

extern "C" void kernel_launch(void* const* d_in, const int* in_sizes, int n_in,
                              void* d_out, int out_size, void* d_ws, size_t ws_size,
                              hipStream_t stream) {
    const f32x4* x4  = (const f32x4*)d_in[0];
    const int*   dur = (const int*)d_in[1];
    const int*   ml  = (const int*)d_in[2];
    float*       out = (float*)d_out;

    length_regulator_kernel<<<dim3(NBLK), dim3(256), 0, stream>>>(x4, dur, ml, out);
}

// Round 10
// 264.043 us; speedup vs baseline: 1.0229x; 1.0229x over previous
//
#include <hip/hip_runtime.h>

// LengthRegulator: expand x[B,L,D] along L per integer durations into out[B,T,D].
// B=64, L=256, D=512, T=max_length=1792. Out: (out [B,T,D] f32, max_length).
//
// v10 = v5 (best measured, dur 263.7us) + wave-uniform tri-path copy batches.
// Ledger: v5 263.7 < dedupe 266.0 < split 267.5 < NT 269.8-271.8 < TILE128 270.1.
// Durations avg 3.5/8 -> ~half of all frames are zero-tail; v5 paid a clamped
// row-0 load + select + idx_s read for each. idx is non-decreasing, so each
// tile splits at wave-uniform nd = clamp(total - t0, 0, TILE):
//   batch fully < nd  -> raw load+store (no clamp, no select)
//   batch fully >= nd -> pure zero-store stream (fill-like, no loads/LDS)
//   straddling batch  -> v5 clamp+select body (at most one per tile)
// Plus shuffle scan (2 barriers, R8-proven). Everything else identical to v5:
// TILE=64, 1792 blocks, interleaved frames, batch-4 independent loads,
// plain stores (NT measured 4.16 vs 6.4 TB/s), XCD-locality swizzle.

#define BB 64
#define LL 256
#define DD 512
#define TT 1792
#define D4 (DD / 4)          // 128 float4 per row
#define TILE 64              // frames per block; TT = 28 * TILE exact
#define NBT (TT / TILE)      // 28 t-blocks per b
#define NBLK (BB * NBT)      // 1792 blocks

typedef float f32x4 __attribute__((ext_vector_type(4)));

__global__ __launch_bounds__(256) void length_regulator_kernel(
    const f32x4* __restrict__ x4,       // [B, L, D4]
    const int*   __restrict__ dur,      // [B, L]
    const int*   __restrict__ maxlen,   // [1]
    float*       __restrict__ out)      // [B*T*D + 1]
{
    __shared__ int wsum[4];
    __shared__ int idx_s[TILE];
    const int tid = threadIdx.x;

    // XCD-locality swizzle: XCD k owns b in [8k, 8k+8).
    const int bid  = blockIdx.x;
    const int virt = (bid & 7) * (NBLK / 8) + (bid >> 3);
    const int b    = virt / NBT;
    const int t0   = (virt % NBT) * TILE;

    // --- inclusive scan of durations: wave shuffle scan + 4-wave combine ---
    // ALPHA = 1.0 -> round(d * 1.0) == d
    int d = dur[b * LL + tid];
    int c = d;
    #pragma unroll
    for (int off = 1; off < 64; off <<= 1) {
        int u = __shfl_up(c, off, 64);
        if ((tid & 63) >= off) c += u;
    }
    if (tid < TILE) idx_s[tid] = -1;          // -1 = "zero frame"
    if ((tid & 63) == 63) wsum[tid >> 6] = c; // wave totals
    __syncthreads();
    int total;
    {
        const int s0 = wsum[0], s1 = wsum[1], s2 = wsum[2], s3 = wsum[3];
        const int wid = tid >> 6;
        total = s0 + s1 + s2 + s3;
        c += (wid > 0 ? s0 : 0) + (wid > 1 ? s1 : 0) + (wid > 2 ? s2 : 0);
        // all-zero row: d[0] = 1 -> cum[j] = 1 for all j
        if (total == 0) { c = 1; d = (tid == 0) ? 1 : 0; total = 1; }
    }

    // --- scatter: thread j stamps idx over [c-d, c) ∩ [t0, t0+TILE) ---
    // Reproduces searchsorted(cum, t, 'right'). <= 7 LDS writes/thread.
    {
        const int lo = max(c - d, t0);
        const int hi = min(c, t0 + TILE);
        for (int t = lo; t < hi; ++t) idx_s[t - t0] = tid;
    }
    __syncthreads();

    // --- copy: 2 groups x 128 lanes; one D-row per group per iter ---
    // Tri-path per 4-batch, all conditions wave-uniform (nd uniform):
    const int nd    = min(max(total - t0, 0), TILE);  // data frames in tile
    const int group = tid >> 7;   // 0..1
    const int lane  = tid & 127;  // float4 index within row
    const f32x4 z   = (f32x4)(0.f);
    const f32x4* __restrict__ xrow = x4 + (size_t)b * LL * D4;
    f32x4* __restrict__ outb = (f32x4*)out + ((size_t)b * TT + t0) * D4;

    #pragma unroll
    for (int itb = 0; itb < TILE / 2; itb += 4) {
        const int ta = (itb + 0) * 2 + group;
        const int tb = (itb + 1) * 2 + group;
        const int tc = (itb + 2) * 2 + group;
        const int td = (itb + 3) * 2 + group;
        if (td < nd) {
            // all-data: idx guaranteed valid (t < total) — raw load+store
            f32x4 va = xrow[idx_s[ta] * D4 + lane];
            f32x4 vb = xrow[idx_s[tb] * D4 + lane];
            f32x4 vc = xrow[idx_s[tc] * D4 + lane];
            f32x4 ve = xrow[idx_s[td] * D4 + lane];
            outb[ta * D4 + lane] = va;
            outb[tb * D4 + lane] = vb;
            outb[tc * D4 + lane] = vc;
            outb[td * D4 + lane] = ve;
        } else if (ta >= nd) {
            // all-zero: pure store stream, no loads, no LDS reads
            outb[ta * D4 + lane] = z;
            outb[tb * D4 + lane] = z;
            outb[tc * D4 + lane] = z;
            outb[td * D4 + lane] = z;
        } else {
            // straddling batch (at most one per tile): v5 clamp+select body
            const int ia = idx_s[ta];
            const int ib = idx_s[tb];
            const int ic = idx_s[tc];
            const int ie = idx_s[td];
            f32x4 va = xrow[max(ia, 0) * D4 + lane];
            f32x4 vb = xrow[max(ib, 0) * D4 + lane];
            f32x4 vc = xrow[max(ic, 0) * D4 + lane];
            f32x4 ve = xrow[max(ie, 0) * D4 + lane];
            va = (ia >= 0) ? va : z;
            vb = (ib >= 0) ? vb : z;
            vc = (ic >= 0) ? vc : z;
            ve = (ie >= 0) ? ve : z;
            outb[ta * D4 + lane] = va;
            outb[tb * D4 + lane] = vb;
            outb[tc * D4 + lane] = vc;
            outb[td * D4 + lane] = ve;
        }
    }

    // --- output 1: max_length as float, one thread writes it ---
    if (virt == 0 && tid == 0) {
        out[(size_t)BB * TT * DD] = (float)maxlen[0];
    }
}

extern "C" void kernel_launch(void* const* d_in, const int* in_sizes, int n_in,
                              void* d_out, int out_size, void* d_ws, size_t ws_size,
                              hipStream_t stream) {
    const f32x4* x4  = (const f32x4*)d_in[0];
    const int*   dur = (const int*)d_in[1];
    const int*   ml  = (const int*)d_in[2];
    float*       out = (float*)d_out;

    length_regulator_kernel<<<dim3(NBLK), dim3(256), 0, stream>>>(x4, dur, ml, out);
}